// Round 7
// baseline (332.161 us; speedup 1.0000x reference)
//
#include <hip/hip_runtime.h>
#include <hip/hip_bf16.h>

typedef __attribute__((ext_vector_type(8))) __bf16 bf16x8;
typedef __attribute__((ext_vector_type(4))) float floatx4;
typedef __attribute__((ext_vector_type(4))) int intx4;

constexpr int N_NODES = 100000;
constexpr int P_PERM  = 200000;

// ws layout (bytes)
constexpr size_t W2F_OFF  = 0;          // [16][2][4][64][8] bf16 = 131072
constexpr size_t WLF_OFF  = 131072;     // 8192
constexpr size_t WD1F_OFF = 139264;     // 16384
constexpr size_t BE_OFF   = 155648;     // P*16 u8 = 3.2e6
constexpr size_t NFBF_OFF = 3355648;    // [N][64] bf16 = 12.8e6
constexpr size_t H2_OFF   = 16155648;   // [P][64] fp32 = 51.2e6
constexpr size_t RP_OFF   = 67355648;   // row_ptr [N+1] int = 400004 -> pad 400016
constexpr size_t CUR_OFF  = 67755664;   // hist/cursor [N] int = 400000
constexpr size_t CIDX_OFF = 68155664;   // [P] int = 800000
constexpr size_t CSUM_OFF = 68955664;   // chunk sums [49] int
constexpr size_t WS_NEED_BF16 = 16155648;
constexpr size_t WS_NEED_CSR  = 68956000;

constexpr int SCAN_CHUNK = 2048;
constexpr int NCHUNK = 49;  // 49*2048 = 100352 >= 100000

// ---- fused prep ----
// [0,6250) zero out (fallback only); [6250,6554) frag swizzle; [6554,9679) nfbf;
// [9679,12804) be_pack; [12804,13195) hist zero
__global__ void prep_all_kernel(float4* __restrict__ out,
                                const float* __restrict__ weights,
                                const float* __restrict__ w_lin,
                                const float* __restrict__ w_deg1,
                                const float* __restrict__ nfeat,
                                const int* __restrict__ e2p_col,
                                const int* __restrict__ edge_feat_idx,
                                __bf16* __restrict__ ws_bf,
                                int do_zero_out) {
  int b = blockIdx.x;
  int t = threadIdx.x;
  if (b < 6250) {
    if (do_zero_out) out[b * 256 + t] = make_float4(0.f, 0.f, 0.f, 0.f);
  } else if (b < 6554) {
    int i = (b - 6250) * 256 + t;
    if (i < 65536) {
      int j = i & 7, l = (i >> 3) & 63, ct = (i >> 9) & 3, ks = (i >> 11) & 1, a = i >> 12;
      int k = ks * 32 + (l >> 4) * 8 + j;
      int c = ct * 16 + (l & 15);
      ws_bf[W2F_OFF / 2 + i] = (__bf16)weights[k * 1024 + c * 16 + a];
    } else if (i < 65536 + 4096) {
      int i2 = i - 65536;
      int j = i2 & 7, l = (i2 >> 3) & 63, ct = (i2 >> 9) & 3, ks = (i2 >> 11) & 1;
      int k = ks * 32 + (l >> 4) * 8 + j;
      int c = ct * 16 + (l & 15);
      ws_bf[WLF_OFF / 2 + i2] = (__bf16)w_lin[c * 64 + k];
    } else if (i < 65536 + 4096 + 8192) {
      int i3 = i - 65536 - 4096;
      int j = i3 & 7, l = (i3 >> 3) & 63, ct = (i3 >> 9) & 3, ks = (i3 >> 11) & 3;
      int k = ks * 32 + (l >> 4) * 8 + j;
      int c = ct * 16 + (l & 15);
      ws_bf[WD1F_OFF / 2 + i3] = (__bf16)w_deg1[c * 128 + k];
    }
  } else if (b < 9679) {
    int i = (b - 6554) * 256 + t;
    if (i < N_NODES * 8) {
      float4 a = *(const float4*)(nfeat + (size_t)i * 8);
      float4 c = *(const float4*)(nfeat + (size_t)i * 8 + 4);
      bf16x8 o;
      o[0] = (__bf16)a.x; o[1] = (__bf16)a.y; o[2] = (__bf16)a.z; o[3] = (__bf16)a.w;
      o[4] = (__bf16)c.x; o[5] = (__bf16)c.y; o[6] = (__bf16)c.z; o[7] = (__bf16)c.w;
      *(bf16x8*)(ws_bf + NFBF_OFF / 2 + (size_t)i * 8) = o;
    }
  } else if (b < 12804) {
    int i = (b - 9679) * 256 + t;
    if (i < P_PERM * 4) {
      int4 ec = ((const int4*)e2p_col)[i];
      unsigned v = (unsigned)(edge_feat_idx[ec.x] & 0xff)
                 | ((unsigned)(edge_feat_idx[ec.y] & 0xff) << 8)
                 | ((unsigned)(edge_feat_idx[ec.z] & 0xff) << 16)
                 | ((unsigned)(edge_feat_idx[ec.w] & 0xff) << 24);
      ((unsigned*)((char*)ws_bf + BE_OFF))[i] = v;
    }
  } else {
    int i = (b - 12804) * 256 + t;
    if (i < N_NODES) ((int*)((char*)ws_bf + CUR_OFF))[i] = 0;
  }
}

__global__ void hist_kernel(const int* __restrict__ pool_row, int* __restrict__ hist) {
  int i = blockIdx.x * 256 + threadIdx.x;
  if (i < P_PERM) atomicAdd(&hist[pool_row[i]], 1);
}

__global__ void scan1_kernel(const int* __restrict__ hist, int* __restrict__ csum) {
  __shared__ int red[256];
  int b = blockIdx.x, t = threadIdx.x;
  int s = 0;
  #pragma unroll
  for (int j = 0; j < 8; ++j) {
    int i = b * SCAN_CHUNK + t * 8 + j;
    s += (i < N_NODES) ? hist[i] : 0;
  }
  red[t] = s;
  __syncthreads();
  for (int off = 128; off > 0; off >>= 1) {
    if (t < off) red[t] += red[t + off];
    __syncthreads();
  }
  if (t == 0) csum[b] = red[0];
}

__global__ void scan2_kernel(int* __restrict__ csum, int* __restrict__ row_ptr) {
  if (threadIdx.x == 0) {
    int acc = 0;
    for (int i = 0; i < NCHUNK; ++i) {
      int v = csum[i];
      csum[i] = acc;
      acc += v;
    }
    row_ptr[N_NODES] = acc;  // == P_PERM
  }
}

__global__ void scan3_kernel(const int* __restrict__ csum,
                             int* __restrict__ hist_cursor,  // in: hist, out: cursor
                             int* __restrict__ row_ptr) {
  __shared__ int sc[257];
  int b = blockIdx.x, t = threadIdx.x;
  int v[8];
  int s = 0;
  #pragma unroll
  for (int j = 0; j < 8; ++j) {
    int i = b * SCAN_CHUNK + t * 8 + j;
    v[j] = (i < N_NODES) ? hist_cursor[i] : 0;
    s += v[j];
  }
  sc[t + 1] = s;
  if (t == 0) sc[0] = 0;
  __syncthreads();
  // Hillis-Steele inclusive scan on sc[1..256]
  for (int off = 1; off < 256; off <<= 1) {
    int x = (t >= off) ? sc[t + 1 - off] : 0;
    __syncthreads();
    sc[t + 1] += x;
    __syncthreads();
  }
  int excl = csum[b] + sc[t];
  #pragma unroll
  for (int j = 0; j < 8; ++j) {
    int i = b * SCAN_CHUNK + t * 8 + j;
    if (i < N_NODES) {
      row_ptr[i] = excl;
      hist_cursor[i] = excl;
    }
    excl += v[j];
  }
}

__global__ void scatter_kernel(const int* __restrict__ pool_row,
                               int* __restrict__ cursor,
                               int* __restrict__ cidx) {
  int i = blockIdx.x * 256 + threadIdx.x;
  if (i < P_PERM) {
    int pos = atomicAdd(&cursor[pool_row[i]], 1);
    cidx[pos] = i;
  }
}

// ---- Phase B: out[n] = sum_{p in csr[n]} pool_val[p] * h2[p] ----
__global__ __launch_bounds__(256, 8) void pool_kernel(
    const int* __restrict__ row_ptr, const int* __restrict__ cidx,
    const float* __restrict__ pool_val, const float* __restrict__ h2,
    float* __restrict__ out) {
  int g = blockIdx.x * 256 + threadIdx.x;
  int n = g >> 2, qd = g & 3;
  if (n >= N_NODES) return;
  int s = row_ptr[n], e = row_ptr[n + 1];
  floatx4 a0 = {0,0,0,0}, a1 = {0,0,0,0}, a2 = {0,0,0,0}, a3 = {0,0,0,0};
  for (int i = s; i < e; ++i) {
    int p = cidx[i];
    float pv = pool_val[p];
    const float* hr = h2 + (size_t)p * 64 + qd * 16;
    floatx4 h0 = *(const floatx4*)(hr + 0);
    floatx4 h1 = *(const floatx4*)(hr + 4);
    floatx4 h2v = *(const floatx4*)(hr + 8);
    floatx4 h3 = *(const floatx4*)(hr + 12);
    a0 += pv * h0; a1 += pv * h1; a2 += pv * h2v; a3 += pv * h3;
  }
  float* orow = out + (size_t)n * 64 + qd * 16;
  *(floatx4*)(orow + 0) = a0;
  *(floatx4*)(orow + 4) = a1;
  *(floatx4*)(orow + 8) = a2;
  *(floatx4*)(orow + 12) = a3;
}

template <bool BF16FEAT, bool CSR>
__global__ __launch_bounds__(256, 4) void lrp_mfma_kernel(
    const float* __restrict__ nfeat,
    const float* __restrict__ degs,
    const float* __restrict__ n2p_val,
    const float* __restrict__ e2p_val,
    const float* __restrict__ pool_val,
    const float* __restrict__ bias,
    const float* __restrict__ w_deg0,
    const float* __restrict__ b_deg0,
    const float* __restrict__ b_deg1,
    const float* __restrict__ b_lin,
    const float* __restrict__ bond_emb,
    const int* __restrict__ n2p_col,
    const int* __restrict__ pool_row,
    const __bf16* __restrict__ ws_bf,
    float* __restrict__ h2out,
    float* __restrict__ out) {
  __shared__ __align__(16) char fraglds[2][8192];
  __shared__ __align__(16) __bf16 sbond[4][72];
  __shared__ __align__(16) float swdeg0[128][4];
  __shared__ float sbd0[128];
  __shared__ float sbias[64];
  __shared__ float sblin[64];
  __shared__ float sbd1[64];
  __shared__ __align__(16) __bf16 hs[4][2][16][72];

  const int t = threadIdx.x;
  const int w = t >> 6;
  const int l = t & 63;
  const int m = l & 15;
  const int q = l >> 4;
  const int pbase = blockIdx.x * 128 + w * 32;
  int pb[2] = {pbase, pbase + 16};
  bool valid[2];
  int pbc[2];
  #pragma unroll
  for (int pt = 0; pt < 2; ++pt) {
    valid[pt] = pb[pt] < P_PERM;
    pbc[pt] = valid[pt] ? pb[pt] : (P_PERM - 16);
  }

  if (t < 256) sbond[t >> 6][t & 63] = (__bf16)bond_emb[t];
  if (t < 128) {
    *(float4*)&swdeg0[t][0] = *(const float4*)(w_deg0 + t * 4);
    sbd0[t] = b_deg0[t];
  } else if (t < 192) {
    int c = t - 128;
    sbias[c] = bias[c]; sblin[c] = b_lin[c]; sbd1[c] = b_deg1[c];
  }

  const __bf16* __restrict__ nfbf = ws_bf + NFBF_OFF / 2;
  const bf16x8* __restrict__ WLv  = (const bf16x8*)(ws_bf + WLF_OFF / 2);
  const bf16x8* __restrict__ WD1v = (const bf16x8*)(ws_bf + WD1F_OFF / 2);
  const unsigned* __restrict__ bep = (const unsigned*)((const char*)ws_bf + BE_OFF);
  const char* __restrict__ W2bytes = (const char*)ws_bf + W2F_OFF;

  // wave-cooperative idx preloads (cover all 16 rounds)
  intx4 nvx[2], evx[2], ncx[2];
  int bex[2];
  #pragma unroll
  for (int pt = 0; pt < 2; ++pt) {
    size_t rb = (size_t)pbc[pt] * 16;
    nvx[pt] = *(const intx4*)(n2p_val + rb + 4 * l);
    evx[pt] = *(const intx4*)(e2p_val + rb + 4 * l);
    ncx[pt] = *(const intx4*)(n2p_col + rb + 4 * l);
    bex[pt] = (int)bep[(size_t)pbc[pt] * 4 + l];
  }
  const int selbase = m * 16;

  auto stage = [&](int a, int buf) {
    #pragma unroll
    for (int j = 0; j < 2; ++j) {
      const char* g = W2bytes + (size_t)a * 8192 + (w * 2 + j) * 1024 + l * 16;
      char* lds = &fraglds[buf][(w * 2 + j) * 1024];
      __builtin_amdgcn_global_load_lds(
          (const __attribute__((address_space(1))) unsigned*)g,
          (__attribute__((address_space(3))) unsigned*)lds, 16, 0, 0);
    }
  };
  auto gath = [&](int nc, bf16x8* g) {
    #pragma unroll
    for (int ks = 0; ks < 2; ++ks) {
      int k0 = ks * 32 + q * 8;
      if (BF16FEAT) {
        g[ks] = *(const bf16x8*)(nfbf + (size_t)nc * 64 + k0);
      } else {
        float4 n0 = *(const float4*)(nfeat + (size_t)nc * 64 + k0);
        float4 n1 = *(const float4*)(nfeat + (size_t)nc * 64 + k0 + 4);
        bf16x8 o;
        o[0] = (__bf16)n0.x; o[1] = (__bf16)n0.y; o[2] = (__bf16)n0.z; o[3] = (__bf16)n0.w;
        o[4] = (__bf16)n1.x; o[5] = (__bf16)n1.y; o[6] = (__bf16)n1.z; o[7] = (__bf16)n1.w;
        g[ks] = o;
      }
    }
  };

  floatx4 acc[2][4] = {};
  float dsreg[2][4];
  float nv0[2], ev0[2];
  int nc0[2], be0[2];
  bf16x8 g_cur[2][2], g_nxt[2][2];

  #pragma unroll
  for (int pt = 0; pt < 2; ++pt) {
    nv0[pt] = __int_as_float(__builtin_amdgcn_ds_bpermute(selbase, nvx[pt][0]));
    ev0[pt] = __int_as_float(__builtin_amdgcn_ds_bpermute(selbase, evx[pt][0]));
    nc0[pt] = __builtin_amdgcn_ds_bpermute(selbase, ncx[pt][0]);
    be0[pt] = (__builtin_amdgcn_ds_bpermute(selbase, bex[pt])) & 0xff;
    gath(nc0[pt], g_cur[pt]);
  }
  stage(0, 0);
  __syncthreads();

  #pragma unroll
  for (int a = 0; a < 16; ++a) {
    const int buf = a & 1;
    float nv1[2], ev1[2];
    int nc1[2], be1[2];
    if (a < 15) {
      const int an = a + 1;
      const int sel1 = selbase + (an >> 2) * 4;
      const int sl = an & 3;
      #pragma unroll
      for (int pt = 0; pt < 2; ++pt) {
        nv1[pt] = __int_as_float(__builtin_amdgcn_ds_bpermute(sel1, nvx[pt][sl]));
        ev1[pt] = __int_as_float(__builtin_amdgcn_ds_bpermute(sel1, evx[pt][sl]));
        nc1[pt] = __builtin_amdgcn_ds_bpermute(sel1, ncx[pt][sl]);
        be1[pt] = (__builtin_amdgcn_ds_bpermute(sel1, bex[pt]) >> (sl * 8)) & 0xff;
      }
      stage(a + 1, buf ^ 1);
      #pragma unroll
      for (int pt = 0; pt < 2; ++pt) gath(nc1[pt], g_nxt[pt]);
    }

    bf16x8 afv[2][2];
    #pragma unroll
    for (int pt = 0; pt < 2; ++pt) {
      #pragma unroll
      for (int ks = 0; ks < 2; ++ks) {
        bf16x8 eb = *(const bf16x8*)&sbond[be0[pt]][ks * 32 + q * 8];
        bf16x8 af;
        #pragma unroll
        for (int j = 0; j < 8; ++j)
          af[j] = (__bf16)fmaf(nv0[pt], (float)g_cur[pt][ks][j],
                               ev0[pt] * (float)eb[j]);
        afv[pt][ks] = af;
      }
    }
    #pragma unroll
    for (int ks = 0; ks < 2; ++ks)
      #pragma unroll
      for (int ct = 0; ct < 4; ++ct) {
        bf16x8 frag = *(const bf16x8*)&fraglds[buf][((ks * 4 + ct) * 64 + l) * 16];
        acc[0][ct] = __builtin_amdgcn_mfma_f32_16x16x32_bf16(afv[0][ks], frag, acc[0][ct], 0, 0, 0);
        acc[1][ct] = __builtin_amdgcn_mfma_f32_16x16x32_bf16(afv[1][ks], frag, acc[1][ct], 0, 0, 0);
      }

    if (a == 0 || a == 5 || a == 10 || a == 15) {
      const int jj = a / 5;
      #pragma unroll
      for (int pt = 0; pt < 2; ++pt)
        dsreg[pt][jj] = nv0[pt] * degs[nc0[pt]];
    }

    if (a < 15) {
      __syncthreads();
      #pragma unroll
      for (int pt = 0; pt < 2; ++pt) {
        nv0[pt] = nv1[pt]; ev0[pt] = ev1[pt]; nc0[pt] = nc1[pt]; be0[pt] = be1[pt];
        g_cur[pt][0] = g_nxt[pt][0]; g_cur[pt][1] = g_nxt[pt][1];
      }
    }
  }

  // ---- hr = relu(acc + bias) -> LDS (A-frag layout) -> @ w_lin^T ----
  floatx4 acc2[2][4] = {};
  {
    #pragma unroll
    for (int pt = 0; pt < 2; ++pt)
      #pragma unroll
      for (int ct = 0; ct < 4; ++ct) {
        float bv = sbias[ct * 16 + m];
        #pragma unroll
        for (int rr = 0; rr < 4; ++rr)
          hs[w][pt][q * 4 + rr][ct * 16 + m] =
              (__bf16)fmaxf(acc[pt][ct][rr] + bv, 0.0f);
      }
    #pragma unroll
    for (int pt = 0; pt < 2; ++pt)
      #pragma unroll
      for (int ks = 0; ks < 2; ++ks) {
        bf16x8 af2 = *(const bf16x8*)&hs[w][pt][m][ks * 32 + q * 8];
        #pragma unroll
        for (int ct = 0; ct < 4; ++ct) {
          bf16x8 frag = WLv[(ks * 4 + ct) * 64 + l];
          acc2[pt][ct] = __builtin_amdgcn_mfma_f32_16x16x32_bf16(af2, frag, acc2[pt][ct], 0, 0, 0);
        }
      }
  }

  // ---- g-MLP ----
  floatx4 gacc[2][4] = {};
  #pragma unroll
  for (int ks = 0; ks < 4; ++ks) {
    const int k0 = ks * 32 + q * 8;
    bf16x8 af[2];
    #pragma unroll
    for (int j = 0; j < 8; ++j) {
      int k = k0 + j;
      float4 wr = *(const float4*)&swdeg0[k][0];
      float bk = sbd0[k];
      #pragma unroll
      for (int pt = 0; pt < 2; ++pt) {
        float v = bk;
        v = fmaf(dsreg[pt][0], wr.x, v);
        v = fmaf(dsreg[pt][1], wr.y, v);
        v = fmaf(dsreg[pt][2], wr.z, v);
        v = fmaf(dsreg[pt][3], wr.w, v);
        af[pt][j] = (__bf16)fmaxf(v, 0.0f);
      }
    }
    #pragma unroll
    for (int ct = 0; ct < 4; ++ct) {
      bf16x8 frag = WD1v[(ks * 4 + ct) * 64 + l];
      gacc[0][ct] = __builtin_amdgcn_mfma_f32_16x16x32_bf16(af[0], frag, gacc[0][ct], 0, 0, 0);
      gacc[1][ct] = __builtin_amdgcn_mfma_f32_16x16x32_bf16(af[1], frag, gacc[1][ct], 0, 0, 0);
    }
  }

  // ---- h2 = (acc2 + b_lin) * (gacc + b_deg1) ----
  if (CSR) {
    // plain stores to dense h2 buffer; pool applied in phase B
    #pragma unroll
    for (int pt = 0; pt < 2; ++pt) {
      if (!valid[pt]) continue;
      #pragma unroll
      for (int rr = 0; rr < 4; ++rr) {
        float* hrow = h2out + (size_t)(pb[pt] + q * 4 + rr) * 64 + m;
        #pragma unroll
        for (int ct = 0; ct < 4; ++ct) {
          float h2 = (acc2[pt][ct][rr] + sblin[ct * 16 + m]) *
                     (gacc[pt][ct][rr] + sbd1[ct * 16 + m]);
          hrow[ct * 16] = h2;
        }
      }
    }
  } else {
    #pragma unroll
    for (int pt = 0; pt < 2; ++pt) {
      if (!valid[pt]) continue;
      intx4   pr4 = *(const intx4*)(pool_row + pb[pt] + q * 4);
      floatx4 pv4 = *(const floatx4*)(pool_val + pb[pt] + q * 4);
      #pragma unroll
      for (int rr = 0; rr < 4; ++rr) {
        float* orow = out + (size_t)pr4[rr] * 64;
        float pv = pv4[rr];
        #pragma unroll
        for (int ct = 0; ct < 4; ++ct) {
          float h2 = (acc2[pt][ct][rr] + sblin[ct * 16 + m]) *
                     (gacc[pt][ct][rr] + sbd1[ct * 16 + m]);
          atomicAdd(orow + ct * 16 + m, pv * h2);
        }
      }
    }
  }
}

extern "C" void kernel_launch(void* const* d_in, const int* in_sizes, int n_in,
                              void* d_out, int out_size, void* d_ws, size_t ws_size,
                              hipStream_t stream) {
  const float* nfeat    = (const float*)d_in[0];
  const float* degs     = (const float*)d_in[1];
  const float* n2p_val  = (const float*)d_in[2];
  const float* e2p_val  = (const float*)d_in[3];
  const float* pool_val = (const float*)d_in[4];
  const float* weights  = (const float*)d_in[5];
  const float* bias     = (const float*)d_in[6];
  const float* w_deg0   = (const float*)d_in[7];
  const float* b_deg0   = (const float*)d_in[8];
  const float* w_deg1   = (const float*)d_in[9];
  const float* b_deg1   = (const float*)d_in[10];
  const float* w_lin    = (const float*)d_in[11];
  const float* b_lin    = (const float*)d_in[12];
  const float* bond_emb = (const float*)d_in[13];
  const int* edge_feat_idx = (const int*)d_in[14];
  const int* n2p_col    = (const int*)d_in[16];
  const int* e2p_col    = (const int*)d_in[18];
  const int* pool_row   = (const int*)d_in[19];

  float* out = (float*)d_out;
  __bf16* ws_bf = (__bf16*)d_ws;
  char* wsb = (char*)d_ws;

  bool bf16feat = ws_size >= WS_NEED_BF16;
  bool csr = ws_size >= WS_NEED_CSR;

  prep_all_kernel<<<13195, 256, 0, stream>>>((float4*)out, weights, w_lin,
                                             w_deg1, nfeat, e2p_col,
                                             edge_feat_idx, ws_bf, csr ? 0 : 1);

  float* h2buf   = (float*)(wsb + H2_OFF);
  int* row_ptr   = (int*)(wsb + RP_OFF);
  int* cursor    = (int*)(wsb + CUR_OFF);
  int* cidx      = (int*)(wsb + CIDX_OFF);
  int* csum      = (int*)(wsb + CSUM_OFF);

  if (csr) {
    hist_kernel<<<(P_PERM + 255) / 256, 256, 0, stream>>>(pool_row, cursor);
    scan1_kernel<<<NCHUNK, 256, 0, stream>>>(cursor, csum);
    scan2_kernel<<<1, 64, 0, stream>>>(csum, row_ptr);
    scan3_kernel<<<NCHUNK, 256, 0, stream>>>(csum, cursor, row_ptr);
    scatter_kernel<<<(P_PERM + 255) / 256, 256, 0, stream>>>(pool_row, cursor, cidx);
  }

  int grid = (P_PERM + 127) / 128;  // 1563
  if (csr) {
    if (bf16feat)
      lrp_mfma_kernel<true, true><<<grid, 256, 0, stream>>>(
          nfeat, degs, n2p_val, e2p_val, pool_val, bias, w_deg0, b_deg0,
          b_deg1, b_lin, bond_emb, n2p_col, pool_row, ws_bf, h2buf, out);
    else
      lrp_mfma_kernel<false, true><<<grid, 256, 0, stream>>>(
          nfeat, degs, n2p_val, e2p_val, pool_val, bias, w_deg0, b_deg0,
          b_deg1, b_lin, bond_emb, n2p_col, pool_row, ws_bf, h2buf, out);
    pool_kernel<<<(N_NODES * 4 + 255) / 256, 256, 0, stream>>>(
        row_ptr, cidx, pool_val, h2buf, out);
  } else {
    if (bf16feat)
      lrp_mfma_kernel<true, false><<<grid, 256, 0, stream>>>(
          nfeat, degs, n2p_val, e2p_val, pool_val, bias, w_deg0, b_deg0,
          b_deg1, b_lin, bond_emb, n2p_col, pool_row, ws_bf, h2buf, out);
    else
      lrp_mfma_kernel<false, false><<<grid, 256, 0, stream>>>(
          nfeat, degs, n2p_val, e2p_val, pool_val, bias, w_deg0, b_deg0,
          b_deg1, b_lin, bond_emb, n2p_col, pool_row, ws_bf, h2buf, out);
  }
}

// Round 8
// 322.240 us; speedup vs baseline: 1.0308x; 1.0308x over previous
//
#include <hip/hip_runtime.h>
#include <hip/hip_bf16.h>

typedef __attribute__((ext_vector_type(8))) __bf16 bf16x8;
typedef __attribute__((ext_vector_type(4))) float floatx4;
typedef __attribute__((ext_vector_type(4))) int intx4;

constexpr int N_NODES = 100000;
constexpr int P_PERM  = 200000;

// ws layout (bytes)
constexpr size_t W2F_OFF  = 0;          // [16][2][4][64][8] bf16 = 131072
constexpr size_t WLF_OFF  = 131072;     // 8192
constexpr size_t WD1F_OFF = 139264;     // 16384
constexpr size_t BE_OFF   = 155648;     // P*16 u8 = 3.2e6
constexpr size_t NFBF_OFF = 3355648;    // [N][64] bf16 = 12.8e6
constexpr size_t H2_OFF   = 16155648;   // [P][64] bf16 = 25.6e6
constexpr size_t RP_OFF   = 41755648;   // row_ptr [N+1] -> pad 400016
constexpr size_t CUR_OFF  = 42155664;   // hist/cursor [N] = 400000
constexpr size_t CIDX_OFF = 42555664;   // [P] int = 800000
constexpr size_t CSUM_OFF = 43355664;   // chunk sums [49]
constexpr size_t WS_NEED_BF16 = 16155648;
constexpr size_t WS_NEED_CSR  = 43356000;

constexpr int SCAN_CHUNK = 2048;
constexpr int NCHUNK = 49;  // 49*2048 >= N

// ---- fused prep ----
__global__ void prep_all_kernel(float4* __restrict__ out,
                                const float* __restrict__ weights,
                                const float* __restrict__ w_lin,
                                const float* __restrict__ w_deg1,
                                const float* __restrict__ nfeat,
                                const int* __restrict__ e2p_col,
                                const int* __restrict__ edge_feat_idx,
                                __bf16* __restrict__ ws_bf,
                                int do_zero_out) {
  int b = blockIdx.x;
  int t = threadIdx.x;
  if (b < 6250) {
    if (do_zero_out) out[b * 256 + t] = make_float4(0.f, 0.f, 0.f, 0.f);
  } else if (b < 6554) {
    int i = (b - 6250) * 256 + t;
    if (i < 65536) {
      int j = i & 7, l = (i >> 3) & 63, ct = (i >> 9) & 3, ks = (i >> 11) & 1, a = i >> 12;
      int k = ks * 32 + (l >> 4) * 8 + j;
      int c = ct * 16 + (l & 15);
      ws_bf[W2F_OFF / 2 + i] = (__bf16)weights[k * 1024 + c * 16 + a];
    } else if (i < 65536 + 4096) {
      int i2 = i - 65536;
      int j = i2 & 7, l = (i2 >> 3) & 63, ct = (i2 >> 9) & 3, ks = (i2 >> 11) & 1;
      int k = ks * 32 + (l >> 4) * 8 + j;
      int c = ct * 16 + (l & 15);
      ws_bf[WLF_OFF / 2 + i2] = (__bf16)w_lin[c * 64 + k];
    } else if (i < 65536 + 4096 + 8192) {
      int i3 = i - 65536 - 4096;
      int j = i3 & 7, l = (i3 >> 3) & 63, ct = (i3 >> 9) & 3, ks = (i3 >> 11) & 3;
      int k = ks * 32 + (l >> 4) * 8 + j;
      int c = ct * 16 + (l & 15);
      ws_bf[WD1F_OFF / 2 + i3] = (__bf16)w_deg1[c * 128 + k];
    }
  } else if (b < 9679) {
    int i = (b - 6554) * 256 + t;
    if (i < N_NODES * 8) {
      float4 a = *(const float4*)(nfeat + (size_t)i * 8);
      float4 c = *(const float4*)(nfeat + (size_t)i * 8 + 4);
      bf16x8 o;
      o[0] = (__bf16)a.x; o[1] = (__bf16)a.y; o[2] = (__bf16)a.z; o[3] = (__bf16)a.w;
      o[4] = (__bf16)c.x; o[5] = (__bf16)c.y; o[6] = (__bf16)c.z; o[7] = (__bf16)c.w;
      *(bf16x8*)(ws_bf + NFBF_OFF / 2 + (size_t)i * 8) = o;
    }
  } else if (b < 12804) {
    int i = (b - 9679) * 256 + t;
    if (i < P_PERM * 4) {
      int4 ec = ((const int4*)e2p_col)[i];
      unsigned v = (unsigned)(edge_feat_idx[ec.x] & 0xff)
                 | ((unsigned)(edge_feat_idx[ec.y] & 0xff) << 8)
                 | ((unsigned)(edge_feat_idx[ec.z] & 0xff) << 16)
                 | ((unsigned)(edge_feat_idx[ec.w] & 0xff) << 24);
      ((unsigned*)((char*)ws_bf + BE_OFF))[i] = v;
    }
  } else {
    int i = (b - 12804) * 256 + t;
    if (i < N_NODES) ((int*)((char*)ws_bf + CUR_OFF))[i] = 0;
  }
}

__global__ void hist_kernel(const int* __restrict__ pool_row, int* __restrict__ hist) {
  int i = blockIdx.x * 256 + threadIdx.x;
  if (i < P_PERM) atomicAdd(&hist[pool_row[i]], 1);
}

__global__ void scan1_kernel(const int* __restrict__ hist, int* __restrict__ csum) {
  __shared__ int red[256];
  int b = blockIdx.x, t = threadIdx.x;
  int s = 0;
  #pragma unroll
  for (int j = 0; j < 8; ++j) {
    int i = b * SCAN_CHUNK + t * 8 + j;
    s += (i < N_NODES) ? hist[i] : 0;
  }
  red[t] = s;
  __syncthreads();
  for (int off = 128; off > 0; off >>= 1) {
    if (t < off) red[t] += red[t + off];
    __syncthreads();
  }
  if (t == 0) csum[b] = red[0];
}

__global__ void scan3_kernel(const int* __restrict__ csum,
                             int* __restrict__ hist_cursor,
                             int* __restrict__ row_ptr) {
  __shared__ int sc[257];
  __shared__ int base;
  int b = blockIdx.x, t = threadIdx.x;
  if (t == 0) {
    int acc = 0;
    for (int i = 0; i < b; ++i) acc += csum[i];
    base = acc;
    if (b == 0) row_ptr[N_NODES] = P_PERM;
  }
  int v[8];
  int s = 0;
  #pragma unroll
  for (int j = 0; j < 8; ++j) {
    int i = b * SCAN_CHUNK + t * 8 + j;
    v[j] = (i < N_NODES) ? hist_cursor[i] : 0;
    s += v[j];
  }
  sc[t + 1] = s;
  if (t == 0) sc[0] = 0;
  __syncthreads();
  for (int off = 1; off < 256; off <<= 1) {
    int x = (t >= off) ? sc[t + 1 - off] : 0;
    __syncthreads();
    sc[t + 1] += x;
    __syncthreads();
  }
  int excl = base + sc[t];
  #pragma unroll
  for (int j = 0; j < 8; ++j) {
    int i = b * SCAN_CHUNK + t * 8 + j;
    if (i < N_NODES) {
      row_ptr[i] = excl;
      hist_cursor[i] = excl;
    }
    excl += v[j];
  }
}

__global__ void scatter_kernel(const int* __restrict__ pool_row,
                               int* __restrict__ cursor,
                               int* __restrict__ cidx) {
  int i = blockIdx.x * 256 + threadIdx.x;
  if (i < P_PERM) {
    int pos = atomicAdd(&cursor[pool_row[i]], 1);
    cidx[pos] = i;
  }
}

// ---- Phase B: out[n] = sum_{p in csr[n]} pool_val[p] * h2[p] (h2 bf16) ----
__global__ __launch_bounds__(256, 8) void pool_kernel(
    const int* __restrict__ row_ptr, const int* __restrict__ cidx,
    const float* __restrict__ pool_val, const __bf16* __restrict__ h2,
    float* __restrict__ out) {
  int g = blockIdx.x * 256 + threadIdx.x;
  int n = g >> 2, qd = g & 3;
  if (n >= N_NODES) return;
  int s = row_ptr[n], e = row_ptr[n + 1];
  float a[16] = {};
  for (int i = s; i < e; ++i) {
    int p = cidx[i];
    float pv = pool_val[p];
    const __bf16* hr = h2 + (size_t)p * 64 + qd * 16;
    bf16x8 v0 = *(const bf16x8*)hr;
    bf16x8 v1 = *(const bf16x8*)(hr + 8);
    #pragma unroll
    for (int j = 0; j < 8; ++j) {
      a[j]     += pv * (float)v0[j];
      a[8 + j] += pv * (float)v1[j];
    }
  }
  float* orow = out + (size_t)n * 64 + qd * 16;
  #pragma unroll
  for (int j = 0; j < 4; ++j)
    *(floatx4*)(orow + j * 4) = *(const floatx4*)&a[j * 4];
}

template <bool BF16FEAT, bool CSR>
__global__ __launch_bounds__(256, 4) void lrp_mfma_kernel(
    const float* __restrict__ nfeat,
    const float* __restrict__ degs,
    const float* __restrict__ n2p_val,
    const float* __restrict__ e2p_val,
    const float* __restrict__ pool_val,
    const float* __restrict__ bias,
    const float* __restrict__ w_deg0,
    const float* __restrict__ b_deg0,
    const float* __restrict__ b_deg1,
    const float* __restrict__ b_lin,
    const float* __restrict__ bond_emb,
    const int* __restrict__ n2p_col,
    const int* __restrict__ pool_row,
    const __bf16* __restrict__ ws_bf,
    __bf16* __restrict__ h2out,
    float* __restrict__ out) {
  __shared__ __align__(16) char fraglds[2][8192];
  __shared__ __align__(16) char swd1[16384];     // WD1 frags staged
  __shared__ __align__(16) __bf16 hs[4][16][72]; // per-wave transform tile
  __shared__ __align__(16) __bf16 sbond[4][72];
  __shared__ __align__(16) float swdeg0[128][4];
  __shared__ float sbd0[128];
  __shared__ float sbias[64];
  __shared__ float sblin[64];
  __shared__ float sbd1[64];

  const int t = threadIdx.x;
  const int w = t >> 6;
  const int l = t & 63;
  const int m = l & 15;
  const int q = l >> 4;
  const int pbase = blockIdx.x * 128 + w * 32;
  int pb[2] = {pbase, pbase + 16};
  bool valid[2];
  int pbc[2];
  #pragma unroll
  for (int pt = 0; pt < 2; ++pt) {
    valid[pt] = pb[pt] < P_PERM;
    pbc[pt] = valid[pt] ? pb[pt] : (P_PERM - 16);
  }

  if (t < 256) sbond[t >> 6][t & 63] = (__bf16)bond_emb[t];
  if (t < 128) {
    *(float4*)&swdeg0[t][0] = *(const float4*)(w_deg0 + t * 4);
    sbd0[t] = b_deg0[t];
  } else if (t < 192) {
    int c = t - 128;
    sbias[c] = bias[c]; sblin[c] = b_lin[c]; sbd1[c] = b_deg1[c];
  }

  const __bf16* __restrict__ nfbf = ws_bf + NFBF_OFF / 2;
  const bf16x8* __restrict__ WLv  = (const bf16x8*)(ws_bf + WLF_OFF / 2);
  const unsigned* __restrict__ bep = (const unsigned*)((const char*)ws_bf + BE_OFF);
  const char* __restrict__ W2bytes = (const char*)ws_bf + W2F_OFF;
  const char* __restrict__ WD1bytes = (const char*)ws_bf + WD1F_OFF;

  // stage WD1 fragment table (16 KB) via LDS-DMA: wave w -> 4 KB
  #pragma unroll
  for (int j = 0; j < 4; ++j) {
    const char* g = WD1bytes + (w * 4 + j) * 1024 + l * 16;
    char* lds = &swd1[(w * 4 + j) * 1024];
    __builtin_amdgcn_global_load_lds(
        (const __attribute__((address_space(1))) unsigned*)g,
        (__attribute__((address_space(3))) unsigned*)lds, 16, 0, 0);
  }

  // wave-cooperative idx preloads (cover all 16 rounds)
  intx4 nvx[2], evx[2], ncx[2];
  int bex[2];
  #pragma unroll
  for (int pt = 0; pt < 2; ++pt) {
    size_t rb = (size_t)pbc[pt] * 16;
    nvx[pt] = *(const intx4*)(n2p_val + rb + 4 * l);
    evx[pt] = *(const intx4*)(e2p_val + rb + 4 * l);
    ncx[pt] = *(const intx4*)(n2p_col + rb + 4 * l);
    bex[pt] = (int)bep[(size_t)pbc[pt] * 4 + l];
  }
  const int selbase = m * 16;

  auto stage = [&](int a, int buf) {
    #pragma unroll
    for (int j = 0; j < 2; ++j) {
      const char* g = W2bytes + (size_t)a * 8192 + (w * 2 + j) * 1024 + l * 16;
      char* lds = &fraglds[buf][(w * 2 + j) * 1024];
      __builtin_amdgcn_global_load_lds(
          (const __attribute__((address_space(1))) unsigned*)g,
          (__attribute__((address_space(3))) unsigned*)lds, 16, 0, 0);
    }
  };
  auto gath = [&](int nc, bf16x8* g) {
    #pragma unroll
    for (int ks = 0; ks < 2; ++ks) {
      int k0 = ks * 32 + q * 8;
      if (BF16FEAT) {
        g[ks] = *(const bf16x8*)(nfbf + (size_t)nc * 64 + k0);
      } else {
        float4 n0 = *(const float4*)(nfeat + (size_t)nc * 64 + k0);
        float4 n1 = *(const float4*)(nfeat + (size_t)nc * 64 + k0 + 4);
        bf16x8 o;
        o[0] = (__bf16)n0.x; o[1] = (__bf16)n0.y; o[2] = (__bf16)n0.z; o[3] = (__bf16)n0.w;
        o[4] = (__bf16)n1.x; o[5] = (__bf16)n1.y; o[6] = (__bf16)n1.z; o[7] = (__bf16)n1.w;
        g[ks] = o;
      }
    }
  };

  floatx4 acc[2][4] = {};
  float dsreg[2][4];
  float nv0[2], ev0[2];
  int nc0[2], be0[2];
  bf16x8 g_cur[2][2], g_nxt[2][2];

  #pragma unroll
  for (int pt = 0; pt < 2; ++pt) {
    nv0[pt] = __int_as_float(__builtin_amdgcn_ds_bpermute(selbase, nvx[pt][0]));
    ev0[pt] = __int_as_float(__builtin_amdgcn_ds_bpermute(selbase, evx[pt][0]));
    nc0[pt] = __builtin_amdgcn_ds_bpermute(selbase, ncx[pt][0]);
    be0[pt] = (__builtin_amdgcn_ds_bpermute(selbase, bex[pt])) & 0xff;
    gath(nc0[pt], g_cur[pt]);
  }
  stage(0, 0);
  __syncthreads();

  #pragma unroll
  for (int a = 0; a < 16; ++a) {
    const int buf = a & 1;
    float nv1[2], ev1[2];
    int nc1[2], be1[2];
    if (a < 15) {
      const int an = a + 1;
      const int sel1 = selbase + (an >> 2) * 4;
      const int sl = an & 3;
      #pragma unroll
      for (int pt = 0; pt < 2; ++pt) {
        nv1[pt] = __int_as_float(__builtin_amdgcn_ds_bpermute(sel1, nvx[pt][sl]));
        ev1[pt] = __int_as_float(__builtin_amdgcn_ds_bpermute(sel1, evx[pt][sl]));
        nc1[pt] = __builtin_amdgcn_ds_bpermute(sel1, ncx[pt][sl]);
        be1[pt] = (__builtin_amdgcn_ds_bpermute(sel1, bex[pt]) >> (sl * 8)) & 0xff;
      }
      stage(a + 1, buf ^ 1);
      #pragma unroll
      for (int pt = 0; pt < 2; ++pt) gath(nc1[pt], g_nxt[pt]);
    }

    bf16x8 afv[2][2];
    #pragma unroll
    for (int pt = 0; pt < 2; ++pt) {
      #pragma unroll
      for (int ks = 0; ks < 2; ++ks) {
        bf16x8 eb = *(const bf16x8*)&sbond[be0[pt]][ks * 32 + q * 8];
        bf16x8 af;
        #pragma unroll
        for (int j = 0; j < 8; ++j)
          af[j] = (__bf16)fmaf(nv0[pt], (float)g_cur[pt][ks][j],
                               ev0[pt] * (float)eb[j]);
        afv[pt][ks] = af;
      }
    }
    #pragma unroll
    for (int ks = 0; ks < 2; ++ks)
      #pragma unroll
      for (int ct = 0; ct < 4; ++ct) {
        bf16x8 frag = *(const bf16x8*)&fraglds[buf][((ks * 4 + ct) * 64 + l) * 16];
        acc[0][ct] = __builtin_amdgcn_mfma_f32_16x16x32_bf16(afv[0][ks], frag, acc[0][ct], 0, 0, 0);
        acc[1][ct] = __builtin_amdgcn_mfma_f32_16x16x32_bf16(afv[1][ks], frag, acc[1][ct], 0, 0, 0);
      }

    if (a == 0 || a == 5 || a == 10 || a == 15) {
      const int jj = a / 5;
      #pragma unroll
      for (int pt = 0; pt < 2; ++pt)
        dsreg[pt][jj] = nv0[pt] * degs[nc0[pt]];
    }

    if (a < 15) {
      __syncthreads();
      #pragma unroll
      for (int pt = 0; pt < 2; ++pt) {
        nv0[pt] = nv1[pt]; ev0[pt] = ev1[pt]; nc0[pt] = nc1[pt]; be0[pt] = be1[pt];
        g_cur[pt][0] = g_nxt[pt][0]; g_cur[pt][1] = g_nxt[pt][1];
      }
    }
  }

  // ---- hr = relu(acc + bias) -> hs (A-frag layout) -> @ w_lin^T ----
  // hs reused sequentially per pt: LDS ops are in-order within a wave.
  floatx4 acc2[2][4] = {};
  #pragma unroll
  for (int pt = 0; pt < 2; ++pt) {
    #pragma unroll
    for (int ct = 0; ct < 4; ++ct) {
      float bv = sbias[ct * 16 + m];
      #pragma unroll
      for (int rr = 0; rr < 4; ++rr)
        hs[w][q * 4 + rr][ct * 16 + m] =
            (__bf16)fmaxf(acc[pt][ct][rr] + bv, 0.0f);
    }
    #pragma unroll
    for (int ks = 0; ks < 2; ++ks) {
      bf16x8 af2 = *(const bf16x8*)&hs[w][m][ks * 32 + q * 8];
      #pragma unroll
      for (int ct = 0; ct < 4; ++ct) {
        bf16x8 frag = WLv[(ks * 4 + ct) * 64 + l];
        acc2[pt][ct] = __builtin_amdgcn_mfma_f32_16x16x32_bf16(af2, frag, acc2[pt][ct], 0, 0, 0);
      }
    }
  }

  // ---- g-MLP (WD1 frags from LDS) ----
  floatx4 gacc[2][4] = {};
  #pragma unroll
  for (int ks = 0; ks < 4; ++ks) {
    const int k0 = ks * 32 + q * 8;
    bf16x8 af[2];
    #pragma unroll
    for (int j = 0; j < 8; ++j) {
      int k = k0 + j;
      float4 wr = *(const float4*)&swdeg0[k][0];
      float bk = sbd0[k];
      #pragma unroll
      for (int pt = 0; pt < 2; ++pt) {
        float v = bk;
        v = fmaf(dsreg[pt][0], wr.x, v);
        v = fmaf(dsreg[pt][1], wr.y, v);
        v = fmaf(dsreg[pt][2], wr.z, v);
        v = fmaf(dsreg[pt][3], wr.w, v);
        af[pt][j] = (__bf16)fmaxf(v, 0.0f);
      }
    }
    #pragma unroll
    for (int ct = 0; ct < 4; ++ct) {
      bf16x8 frag = *(const bf16x8*)&swd1[((ks * 4 + ct) * 64 + l) * 16];
      gacc[0][ct] = __builtin_amdgcn_mfma_f32_16x16x32_bf16(af[0], frag, gacc[0][ct], 0, 0, 0);
      gacc[1][ct] = __builtin_amdgcn_mfma_f32_16x16x32_bf16(af[1], frag, gacc[1][ct], 0, 0, 0);
    }
  }

  // ---- h2 = (acc2 + b_lin) * (gacc + b_deg1) ----
  if (CSR) {
    // transpose through hs, store coalesced bf16 rows (8 rows x 128 B per pass)
    #pragma unroll
    for (int pt = 0; pt < 2; ++pt) {
      if (!valid[pt]) continue;
      #pragma unroll
      for (int ct = 0; ct < 4; ++ct) {
        float bl = sblin[ct * 16 + m];
        float bd = sbd1[ct * 16 + m];
        #pragma unroll
        for (int rr = 0; rr < 4; ++rr) {
          float h2v = (acc2[pt][ct][rr] + bl) * (gacc[pt][ct][rr] + bd);
          hs[w][q * 4 + rr][ct * 16 + m] = (__bf16)h2v;
        }
      }
      #pragma unroll
      for (int pass = 0; pass < 2; ++pass) {
        int row = pass * 8 + (l >> 3);
        bf16x8 v = *(const bf16x8*)&hs[w][row][(l & 7) * 8];
        *(bf16x8*)(h2out + (size_t)(pb[pt] + row) * 64 + (l & 7) * 8) = v;
      }
    }
  } else {
    #pragma unroll
    for (int pt = 0; pt < 2; ++pt) {
      if (!valid[pt]) continue;
      intx4   pr4 = *(const intx4*)(pool_row + pb[pt] + q * 4);
      floatx4 pv4 = *(const floatx4*)(pool_val + pb[pt] + q * 4);
      #pragma unroll
      for (int rr = 0; rr < 4; ++rr) {
        float* orow = out + (size_t)pr4[rr] * 64;
        float pv = pv4[rr];
        #pragma unroll
        for (int ct = 0; ct < 4; ++ct) {
          float h2 = (acc2[pt][ct][rr] + sblin[ct * 16 + m]) *
                     (gacc[pt][ct][rr] + sbd1[ct * 16 + m]);
          atomicAdd(orow + ct * 16 + m, pv * h2);
        }
      }
    }
  }
}

extern "C" void kernel_launch(void* const* d_in, const int* in_sizes, int n_in,
                              void* d_out, int out_size, void* d_ws, size_t ws_size,
                              hipStream_t stream) {
  const float* nfeat    = (const float*)d_in[0];
  const float* degs     = (const float*)d_in[1];
  const float* n2p_val  = (const float*)d_in[2];
  const float* e2p_val  = (const float*)d_in[3];
  const float* pool_val = (const float*)d_in[4];
  const float* weights  = (const float*)d_in[5];
  const float* bias     = (const float*)d_in[6];
  const float* w_deg0   = (const float*)d_in[7];
  const float* b_deg0   = (const float*)d_in[8];
  const float* w_deg1   = (const float*)d_in[9];
  const float* b_deg1   = (const float*)d_in[10];
  const float* w_lin    = (const float*)d_in[11];
  const float* b_lin    = (const float*)d_in[12];
  const float* bond_emb = (const float*)d_in[13];
  const int* edge_feat_idx = (const int*)d_in[14];
  const int* n2p_col    = (const int*)d_in[16];
  const int* e2p_col    = (const int*)d_in[18];
  const int* pool_row   = (const int*)d_in[19];

  float* out = (float*)d_out;
  __bf16* ws_bf = (__bf16*)d_ws;
  char* wsb = (char*)d_ws;

  bool bf16feat = ws_size >= WS_NEED_BF16;
  bool csr = ws_size >= WS_NEED_CSR;

  prep_all_kernel<<<13195, 256, 0, stream>>>((float4*)out, weights, w_lin,
                                             w_deg1, nfeat, e2p_col,
                                             edge_feat_idx, ws_bf, csr ? 0 : 1);

  __bf16* h2buf = (__bf16*)(wsb + H2_OFF);
  int* row_ptr  = (int*)(wsb + RP_OFF);
  int* cursor   = (int*)(wsb + CUR_OFF);
  int* cidx     = (int*)(wsb + CIDX_OFF);
  int* csum     = (int*)(wsb + CSUM_OFF);

  if (csr) {
    hist_kernel<<<(P_PERM + 255) / 256, 256, 0, stream>>>(pool_row, cursor);
    scan1_kernel<<<NCHUNK, 256, 0, stream>>>(cursor, csum);
    scan3_kernel<<<NCHUNK, 256, 0, stream>>>(csum, cursor, row_ptr);
    scatter_kernel<<<(P_PERM + 255) / 256, 256, 0, stream>>>(pool_row, cursor, cidx);
  }

  int grid = (P_PERM + 127) / 128;  // 1563
  if (csr) {
    if (bf16feat)
      lrp_mfma_kernel<true, true><<<grid, 256, 0, stream>>>(
          nfeat, degs, n2p_val, e2p_val, pool_val, bias, w_deg0, b_deg0,
          b_deg1, b_lin, bond_emb, n2p_col, pool_row, ws_bf, h2buf, out);
    else
      lrp_mfma_kernel<false, true><<<grid, 256, 0, stream>>>(
          nfeat, degs, n2p_val, e2p_val, pool_val, bias, w_deg0, b_deg0,
          b_deg1, b_lin, bond_emb, n2p_col, pool_row, ws_bf, h2buf, out);
    pool_kernel<<<(N_NODES * 4 + 255) / 256, 256, 0, stream>>>(
        row_ptr, cidx, pool_val, h2buf, out);
  } else {
    if (bf16feat)
      lrp_mfma_kernel<true, false><<<grid, 256, 0, stream>>>(
          nfeat, degs, n2p_val, e2p_val, pool_val, bias, w_deg0, b_deg0,
          b_deg1, b_lin, bond_emb, n2p_col, pool_row, ws_bf, h2buf, out);
    else
      lrp_mfma_kernel<false, false><<<grid, 256, 0, stream>>>(
          nfeat, degs, n2p_val, e2p_val, pool_val, bias, w_deg0, b_deg0,
          b_deg1, b_lin, bond_emb, n2p_col, pool_row, ws_bf, h2buf, out);
  }
}